// Round 1
// baseline (159.507 us; speedup 1.0000x reference)
//
#include <hip/hip_runtime.h>
#include <stdint.h>

typedef unsigned short u16;
typedef unsigned int   u32;
typedef __attribute__((ext_vector_type(8))) short bhalf8;   // 8 bf16 = 4 VGPRs
typedef __attribute__((ext_vector_type(4))) float f32x4;

#define B_ROWS 4096
#define I_DIM  1024
#define O_DIM  1024
#define N_D    6
#define K_LEG  (I_DIM * N_D)   /* 6144 */

#define BM 64
#define BN 128
#define BK 32

// float -> bf16 round-to-nearest-even (inputs are finite; no NaN handling needed)
__device__ __forceinline__ u16 f2b(float f) {
  u32 u = __float_as_uint(f);
  return (u16)((u + 0x7fffu + ((u >> 16) & 1u)) >> 16);
}

// async global->LDS, 16B per lane; LDS dest = wave-uniform base + lane*16
__device__ __forceinline__ void gld_lds16(const void* g, void* l) {
  __builtin_amdgcn_global_load_lds(
      (const __attribute__((address_space(1))) u32*)(uintptr_t)g,
      (__attribute__((address_space(3))) u32*)(u32)(uintptr_t)l, 16, 0, 0);
}

// ---- prep: Bb[o][i] = bf16(base_weight[i][o]) ----
__global__ void k_prep_bb(const float* __restrict__ w, u16* __restrict__ Bb) {
  int j = blockIdx.x * 256 + threadIdx.x;   // j = o*1024 + i
  int o = j >> 10, i = j & 1023;
  Bb[j] = f2b(w[i * O_DIM + o]);
}

// ---- prep: Bl[o][i*6+d] = bf16(legendre_weight[i][o][d]) ----
__global__ void k_prep_bl(const float* __restrict__ w, u16* __restrict__ Bl) {
  int j = blockIdx.x * 256 + threadIdx.x;   // j = o*1024 + i
  int o = j >> 10, i = j & 1023;
  const float* s = w + ((size_t)i * O_DIM + o) * N_D;   // 24B-aligned
  float2 a = *(const float2*)(s);
  float2 b = *(const float2*)(s + 2);
  float2 c = *(const float2*)(s + 4);
  u32* d = (u32*)(Bl + (size_t)o * K_LEG + (size_t)i * N_D); // 4B-aligned
  d[0] = (u32)f2b(a.x) | ((u32)f2b(a.y) << 16);
  d[1] = (u32)f2b(b.x) | ((u32)f2b(b.y) << 16);
  d[2] = (u32)f2b(c.x) | ((u32)f2b(c.y) << 16);
}

// ---- prep: per-row min/max, Legendre basis, x*P_d -> bf16 ----
__global__ void k_prep_basis(const float* __restrict__ x,
                             u16* __restrict__ Ab, u16* __restrict__ Al) {
  int b = blockIdx.x;
  int t = threadIdx.x;    // 256 threads, 4 elems each
  float4 v = ((const float4*)(x + (size_t)b * I_DIM))[t];
  float mn = fminf(fminf(v.x, v.y), fminf(v.z, v.w));
  float mx = fmaxf(fmaxf(v.x, v.y), fmaxf(v.z, v.w));
  #pragma unroll
  for (int off = 32; off > 0; off >>= 1) {
    mn = fminf(mn, __shfl_xor(mn, off, 64));
    mx = fmaxf(mx, __shfl_xor(mx, off, 64));
  }
  __shared__ float smn[4], smx[4];
  if ((t & 63) == 0) { smn[t >> 6] = mn; smx[t >> 6] = mx; }
  __syncthreads();
  mn = fminf(fminf(smn[0], smn[1]), fminf(smn[2], smn[3]));
  mx = fmaxf(fmaxf(smx[0], smx[1]), fmaxf(smx[2], smx[3]));
  float sc = 2.0f / (mx - mn + 1e-7f);

  float xs[4] = {v.x, v.y, v.z, v.w};
  u32 lb[12];
  #pragma unroll
  for (int e = 0; e < 4; ++e) {
    float xv = xs[e];
    float xn = (xv - mn) * sc - 1.0f;
    float p0 = 1.0f, p1 = xn;
    float p2 = (3.0f * xn * p1 - 1.0f * p0) * (1.0f / 2.0f);
    float p3 = (5.0f * xn * p2 - 2.0f * p1) * (1.0f / 3.0f);
    float p4 = (7.0f * xn * p3 - 3.0f * p2) * (1.0f / 4.0f);
    float p5 = (9.0f * xn * p4 - 4.0f * p3) * (1.0f / 5.0f);
    lb[e * 3 + 0] = (u32)f2b(xv * p0) | ((u32)f2b(xv * p1) << 16);
    lb[e * 3 + 1] = (u32)f2b(xv * p2) | ((u32)f2b(xv * p3) << 16);
    lb[e * 3 + 2] = (u32)f2b(xv * p4) | ((u32)f2b(xv * p5) << 16);
  }
  // A_base: 4 bf16 (8B)
  u32 a0 = (u32)f2b(xs[0]) | ((u32)f2b(xs[1]) << 16);
  u32 a1 = (u32)f2b(xs[2]) | ((u32)f2b(xs[3]) << 16);
  *(uint2*)(Ab + (size_t)b * I_DIM + t * 4) = make_uint2(a0, a1);
  // A_leg: 24 bf16 (48B, 16B-aligned)
  uint4* dl = (uint4*)(Al + (size_t)b * K_LEG + t * 24);
  dl[0] = make_uint4(lb[0], lb[1], lb[2], lb[3]);
  dl[1] = make_uint4(lb[4], lb[5], lb[6], lb[7]);
  dl[2] = make_uint4(lb[8], lb[9], lb[10], lb[11]);
}

// ---- fused GEMM: acc = x@Wb (K=1024) -> silu(acc) -> acc += A_leg@Bl^T (K=6144) ----
__global__ __launch_bounds__(256) void k_gemm(
    const u16* __restrict__ Ab, const u16* __restrict__ Bb,
    const u16* __restrict__ Al, const u16* __restrict__ Bl,
    float* __restrict__ out) {
  __shared__ alignas(16) u16 As[BM * BK];
  __shared__ alignas(16) u16 Bs[BN * BK];

  const int tid  = threadIdx.x;
  const int wave = tid >> 6;
  const int lane = tid & 63;
  const int wr = wave >> 1;            // 0..1: 32-row band
  const int wc = wave & 1;             // 0..1: 64-col band

  // XCD swizzle: XCD c owns the whole column panel by==c (B panel L2-resident)
  int bid  = blockIdx.x;               // 512 blocks, 512%8==0 -> bijective
  int nbid = (bid & 7) * 64 + (bid >> 3);
  const int bx = nbid & 63;
  const int by = nbid >> 6;
  const size_t brow = (size_t)bx * BM;
  const size_t bcol = (size_t)by * BN;

  const int srow = lane >> 2;          // staging: row within 16-row group
  const int scol = (lane & 3) * 8;     // staging: element offset in 32-elem row
  const int kg   = lane >> 4;          // frag k-group 0..3
  const int rr   = lane & 15;          // frag row/col 0..15

  f32x4 acc[2][4] = {};
  const bhalf8* Asv = (const bhalf8*)As;
  const bhalf8* Bsv = (const bhalf8*)Bs;

  auto run_phase = [&](const u16* __restrict__ A, const u16* __restrict__ Bt,
                       int ldk, int nk) {
    for (int kt = 0; kt < nk; ++kt) {
      // stage A tile (64x32): wave w -> rows [16w, 16w+16)
      {
        const u16* g = A + (brow + (size_t)(wave * 16 + srow)) * ldk + kt * BK + scol;
        gld_lds16(g, (void*)(As + wave * 16 * BK));
      }
      // stage B^T tile (128x32): wave w -> rows [32w, 32w+32)
      {
        const u16* g = Bt + (bcol + (size_t)(wave * 32 + srow)) * ldk + kt * BK + scol;
        gld_lds16(g, (void*)(Bs + wave * 32 * BK));
        gld_lds16(g + (size_t)16 * ldk, (void*)(Bs + (wave * 32 + 16) * BK));
      }
      __syncthreads();   // compiler emits vmcnt(0) drain before barrier
      bhalf8 af[2], bf[4];
      #pragma unroll
      for (int m = 0; m < 2; ++m) af[m] = Asv[(wr * 32 + m * 16 + rr) * (BK / 8) + kg];
      #pragma unroll
      for (int n = 0; n < 4; ++n) bf[n] = Bsv[(wc * 64 + n * 16 + rr) * (BK / 8) + kg];
      #pragma unroll
      for (int m = 0; m < 2; ++m)
        #pragma unroll
        for (int n = 0; n < 4; ++n)
          acc[m][n] = __builtin_amdgcn_mfma_f32_16x16x32_bf16(af[m], bf[n], acc[m][n], 0, 0, 0);
      __syncthreads();
    }
  };

  run_phase(Ab, Bb, I_DIM, I_DIM / BK);

  // silu on the base accumulator, in registers
  #pragma unroll
  for (int m = 0; m < 2; ++m)
    #pragma unroll
    for (int n = 0; n < 4; ++n)
      #pragma unroll
      for (int j = 0; j < 4; ++j) {
        float v = acc[m][n][j];
        acc[m][n][j] = v / (1.0f + __expf(-v));
      }

  run_phase(Al, Bl, K_LEG, K_LEG / BK);

  // C/D layout: col = lane&15, row = (lane>>4)*4 + j   [measured m89/m91]
  #pragma unroll
  for (int m = 0; m < 2; ++m)
    #pragma unroll
    for (int n = 0; n < 4; ++n) {
      const size_t r0 = brow + wr * 32 + m * 16 + kg * 4;
      const size_t c  = bcol + wc * 64 + n * 16 + rr;
      #pragma unroll
      for (int j = 0; j < 4; ++j)
        out[(r0 + j) * O_DIM + c] = acc[m][n][j];
    }
}

extern "C" void kernel_launch(void* const* d_in, const int* in_sizes, int n_in,
                              void* d_out, int out_size, void* d_ws, size_t ws_size,
                              hipStream_t stream) {
  const float* x  = (const float*)d_in[0];   // [4096][1024]
  const float* bw = (const float*)d_in[1];   // [1024][1024]
  const float* lw = (const float*)d_in[2];   // [1024][1024][6]
  float* out = (float*)d_out;                // [4096][1024]

  char* w = (char*)d_ws;
  u16* Ab = (u16*)(w);                                  //  8 MiB [4096][1024]
  u16* Al = (u16*)(w + (size_t)8  * 1024 * 1024);       // 48 MiB [4096][6144]
  u16* Bb = (u16*)(w + (size_t)56 * 1024 * 1024);       //  2 MiB [1024][1024]
  u16* Bl = (u16*)(w + (size_t)58 * 1024 * 1024);       // 12 MiB [1024][6144]

  k_prep_bb   <<<dim3((O_DIM * I_DIM) / 256), 256, 0, stream>>>(bw, Bb);
  k_prep_bl   <<<dim3((O_DIM * I_DIM) / 256), 256, 0, stream>>>(lw, Bl);
  k_prep_basis<<<dim3(B_ROWS), 256, 0, stream>>>(x, Ab, Al);
  k_gemm      <<<dim3((B_ROWS / BM) * (O_DIM / BN)), 256, 0, stream>>>(Ab, Bb, Al, Bl, out);
}

// Round 2
// 149.515 us; speedup vs baseline: 1.0668x; 1.0668x over previous
//
#include <hip/hip_runtime.h>
#include <stdint.h>

typedef unsigned short u16;
typedef unsigned int   u32;
typedef __attribute__((ext_vector_type(8))) short bhalf8;   // 8 bf16 = 4 VGPRs
typedef __attribute__((ext_vector_type(4))) float f32x4;

#define B_ROWS 4096
#define I_DIM  1024
#define O_DIM  1024
#define N_D    6
#define K_LEG  (I_DIM * N_D)   /* 6144 */

#define BM 128
#define BN 128
#define BK 32

// float -> bf16 round-to-nearest-even
__device__ __forceinline__ u16 f2b(float f) {
  u32 u = __float_as_uint(f);
  return (u16)((u + 0x7fffu + ((u >> 16) & 1u)) >> 16);
}

// async global->LDS, 16B per lane; LDS dest = wave-uniform base + lane*16
__device__ __forceinline__ void gld_lds16(const void* g, void* l) {
  __builtin_amdgcn_global_load_lds(
      (const __attribute__((address_space(1))) u32*)(uintptr_t)g,
      (__attribute__((address_space(3))) u32*)(u32)(uintptr_t)l, 16, 0, 0);
}

// ---- prep: Bb[o][i] = bf16(base_weight[i][o]) ----
__global__ void k_prep_bb(const float* __restrict__ w, u16* __restrict__ Bb) {
  int j = blockIdx.x * 256 + threadIdx.x;   // j = o*1024 + i
  int o = j >> 10, i = j & 1023;
  Bb[j] = f2b(w[i * O_DIM + o]);
}

// ---- prep: Bl[o][i*6+d] = bf16(legendre_weight[i][o][d]) ----
__global__ void k_prep_bl(const float* __restrict__ w, u16* __restrict__ Bl) {
  int j = blockIdx.x * 256 + threadIdx.x;   // j = o*1024 + i
  int o = j >> 10, i = j & 1023;
  const float* s = w + ((size_t)i * O_DIM + o) * N_D;   // 24B-aligned
  float2 a = *(const float2*)(s);
  float2 b = *(const float2*)(s + 2);
  float2 c = *(const float2*)(s + 4);
  u32* d = (u32*)(Bl + (size_t)o * K_LEG + (size_t)i * N_D); // 4B-aligned, coalesced
  d[0] = (u32)f2b(a.x) | ((u32)f2b(a.y) << 16);
  d[1] = (u32)f2b(b.x) | ((u32)f2b(b.y) << 16);
  d[2] = (u32)f2b(c.x) | ((u32)f2b(c.y) << 16);
}

// ---- prep: per-row min/max, Legendre basis, x*P_d -> bf16 ----
__global__ void k_prep_basis(const float* __restrict__ x,
                             u16* __restrict__ Ab, u16* __restrict__ Al) {
  int b = blockIdx.x;
  int t = threadIdx.x;    // 256 threads, 4 elems each
  float4 v = ((const float4*)(x + (size_t)b * I_DIM))[t];
  float mn = fminf(fminf(v.x, v.y), fminf(v.z, v.w));
  float mx = fmaxf(fmaxf(v.x, v.y), fmaxf(v.z, v.w));
  #pragma unroll
  for (int off = 32; off > 0; off >>= 1) {
    mn = fminf(mn, __shfl_xor(mn, off, 64));
    mx = fmaxf(mx, __shfl_xor(mx, off, 64));
  }
  __shared__ float smn[4], smx[4];
  if ((t & 63) == 0) { smn[t >> 6] = mn; smx[t >> 6] = mx; }
  __syncthreads();
  mn = fminf(fminf(smn[0], smn[1]), fminf(smn[2], smn[3]));
  mx = fmaxf(fmaxf(smx[0], smx[1]), fmaxf(smx[2], smx[3]));
  float sc = 2.0f / (mx - mn + 1e-7f);

  float xs[4] = {v.x, v.y, v.z, v.w};
  u32 lb[12];
  #pragma unroll
  for (int e = 0; e < 4; ++e) {
    float xv = xs[e];
    float xn = (xv - mn) * sc - 1.0f;
    float p0 = 1.0f, p1 = xn;
    float p2 = (3.0f * xn * p1 - 1.0f * p0) * (1.0f / 2.0f);
    float p3 = (5.0f * xn * p2 - 2.0f * p1) * (1.0f / 3.0f);
    float p4 = (7.0f * xn * p3 - 3.0f * p2) * (1.0f / 4.0f);
    float p5 = (9.0f * xn * p4 - 4.0f * p3) * (1.0f / 5.0f);
    lb[e * 3 + 0] = (u32)f2b(xv * p0) | ((u32)f2b(xv * p1) << 16);
    lb[e * 3 + 1] = (u32)f2b(xv * p2) | ((u32)f2b(xv * p3) << 16);
    lb[e * 3 + 2] = (u32)f2b(xv * p4) | ((u32)f2b(xv * p5) << 16);
  }
  u32 a0 = (u32)f2b(xs[0]) | ((u32)f2b(xs[1]) << 16);
  u32 a1 = (u32)f2b(xs[2]) | ((u32)f2b(xs[3]) << 16);
  *(uint2*)(Ab + (size_t)b * I_DIM + t * 4) = make_uint2(a0, a1);
  uint4* dl = (uint4*)(Al + (size_t)b * K_LEG + t * 24);
  dl[0] = make_uint4(lb[0], lb[1], lb[2], lb[3]);
  dl[1] = make_uint4(lb[4], lb[5], lb[6], lb[7]);
  dl[2] = make_uint4(lb[8], lb[9], lb[10], lb[11]);
}

// ---- fused split-K GEMM, m97 structure: 128x128 tile, 4 waves x (4x4 frags) ----
// split 0: base(K=1024) -> silu(acc) -> leg K-steps [0,80)
// split 1: leg K-steps [80,192)
// both atomically add into zeroed out[] (2 contributions -> deterministic)
__global__ __launch_bounds__(256) void k_gemm(
    const u16* __restrict__ Ab, const u16* __restrict__ Bb,
    const u16* __restrict__ Al, const u16* __restrict__ Bl,
    float* __restrict__ out) {
  __shared__ alignas(16) u16 As[BM * BK];
  __shared__ alignas(16) u16 Bs[BN * BK];

  const int tid  = threadIdx.x;
  const int wave = tid >> 6;
  const int lane = tid & 63;
  const int wr = wave >> 1;            // 0..1: 64-row band
  const int wc = wave & 1;             // 0..1: 64-col band

  // XCD swizzle over 512 blocks (512%8==0 -> bijective); both splits of a
  // tile land on the same XCD; XCD c owns column panel by==c (B L2-resident)
  int bid  = blockIdx.x;
  int nb   = (bid & 7) * 64 + (bid >> 3);
  const int split = nb & 1;
  const int tile  = nb >> 1;           // 0..255
  const int bx = tile & 31;            // M-tile
  const int by = tile >> 5;            // N-tile
  const size_t brow = (size_t)bx * BM;
  const size_t bcol = (size_t)by * BN;

  const int srow = lane >> 2;          // staging row within 16-row group
  const int scol = (lane & 3) * 8;     // staging elem offset in 32-elem row
  const int kg   = lane >> 4;          // frag k-group 0..3
  const int rr   = lane & 15;          // frag row/col 0..15

  f32x4 acc[4][4] = {};
  const bhalf8* Asv = (const bhalf8*)As;
  const bhalf8* Bsv = (const bhalf8*)Bs;

  auto run_phase = [&](const u16* __restrict__ A, const u16* __restrict__ Bt,
                       int ldk, int k0, int k1) {
    const u16* ga = A + (brow + (size_t)(wave * 32 + srow)) * ldk + k0 * BK + scol;
    const u16* gb = Bt + (bcol + (size_t)(wave * 32 + srow)) * ldk + k0 * BK + scol;
    const size_t rstep = (size_t)16 * ldk;
    for (int kt = k0; kt < k1; ++kt) {
      // stage A tile (128x32): wave w -> rows [32w, 32w+32)
      gld_lds16(ga,         (void*)(As + wave * 32 * BK));
      gld_lds16(ga + rstep, (void*)(As + (wave * 32 + 16) * BK));
      // stage B^T tile (128x32)
      gld_lds16(gb,         (void*)(Bs + wave * 32 * BK));
      gld_lds16(gb + rstep, (void*)(Bs + (wave * 32 + 16) * BK));
      ga += BK; gb += BK;
      __syncthreads();
      bhalf8 af[4], bf[4];
      #pragma unroll
      for (int m = 0; m < 4; ++m) af[m] = Asv[(wr * 64 + m * 16 + rr) * (BK / 8) + kg];
      #pragma unroll
      for (int n = 0; n < 4; ++n) bf[n] = Bsv[(wc * 64 + n * 16 + rr) * (BK / 8) + kg];
      #pragma unroll
      for (int m = 0; m < 4; ++m)
        #pragma unroll
        for (int n = 0; n < 4; ++n)
          acc[m][n] = __builtin_amdgcn_mfma_f32_16x16x32_bf16(af[m], bf[n], acc[m][n], 0, 0, 0);
      __syncthreads();
    }
  };

  if (split == 0) {
    run_phase(Ab, Bb, I_DIM, 0, I_DIM / BK);   // base GEMM, K=1024
    // silu on base accumulator, in registers
    #pragma unroll
    for (int m = 0; m < 4; ++m)
      #pragma unroll
      for (int n = 0; n < 4; ++n)
        #pragma unroll
        for (int j = 0; j < 4; ++j) {
          float v = acc[m][n][j];
          acc[m][n][j] = v / (1.0f + __expf(-v));
        }
    run_phase(Al, Bl, K_LEG, 0, 80);           // leg K-steps [0,80)
  } else {
    run_phase(Al, Bl, K_LEG, 80, K_LEG / BK);  // leg K-steps [80,192)
  }

  // C/D layout per 16x16 frag: col = lane&15, row = (lane>>4)*4 + j
  #pragma unroll
  for (int m = 0; m < 4; ++m)
    #pragma unroll
    for (int n = 0; n < 4; ++n) {
      const size_t r0 = brow + wr * 64 + m * 16 + kg * 4;
      const size_t c  = bcol + wc * 64 + n * 16 + rr;
      #pragma unroll
      for (int j = 0; j < 4; ++j)
        unsafeAtomicAdd(&out[(r0 + j) * O_DIM + c], acc[m][n][j]);
    }
}

extern "C" void kernel_launch(void* const* d_in, const int* in_sizes, int n_in,
                              void* d_out, int out_size, void* d_ws, size_t ws_size,
                              hipStream_t stream) {
  const float* x  = (const float*)d_in[0];   // [4096][1024]
  const float* bw = (const float*)d_in[1];   // [1024][1024]
  const float* lw = (const float*)d_in[2];   // [1024][1024][6]
  float* out = (float*)d_out;                // [4096][1024]

  char* w = (char*)d_ws;
  u16* Ab = (u16*)(w);                                  //  8 MiB [4096][1024]
  u16* Al = (u16*)(w + (size_t)8  * 1024 * 1024);       // 48 MiB [4096][6144]
  u16* Bb = (u16*)(w + (size_t)56 * 1024 * 1024);       //  2 MiB [1024][1024]
  u16* Bl = (u16*)(w + (size_t)58 * 1024 * 1024);       // 12 MiB [1024][6144]

  hipMemsetAsync(d_out, 0, (size_t)out_size * sizeof(float), stream);
  k_prep_bb   <<<dim3((O_DIM * I_DIM) / 256), 256, 0, stream>>>(bw, Bb);
  k_prep_bl   <<<dim3((O_DIM * I_DIM) / 256), 256, 0, stream>>>(lw, Bl);
  k_prep_basis<<<dim3(B_ROWS), 256, 0, stream>>>(x, Ab, Al);
  k_gemm      <<<dim3(2 * (B_ROWS / BM) * (O_DIM / BN)), 256, 0, stream>>>(Ab, Bb, Al, Bl, out);
}